// Round 7
// baseline (9850.505 us; speedup 1.0000x reference)
//
#include <hip/hip_runtime.h>

typedef unsigned int uint;
typedef unsigned short ushort;
typedef unsigned long long u64;

// MFMA fragment types (16x16x32 bf16 -> 8 bf16 in, 4 fp32 acc)
typedef short s8v __attribute__((ext_vector_type(8)));
typedef float f4v __attribute__((ext_vector_type(4)));

#define S_LEN 512
#define BATCH 64
#define DH    1024
#define DIN   1024
#define HSZ   (64*1024)   // one exchange slot (64 batches x 1024 cols)

union B8 { s8v v; uint u[4]; u64 ull[2]; ushort s[8]; };

__device__ inline ushort f2bf(float f){
  uint u = __builtin_bit_cast(uint, f);
  u += 0x7fffu + ((u >> 16) & 1u);
  return (ushort)(u >> 16);
}
__device__ inline float bf2f(ushort s){
  uint u = ((uint)s) << 16;
  return __builtin_bit_cast(float, u);
}

__device__ inline f4v mfma16(s8v a, s8v b, f4v c){
  return __builtin_amdgcn_mfma_f32_16x16x32_bf16(a, b, c, 0, 0, 0);
}

__device__ inline s8v ld_b8(const ushort* p){
  return *reinterpret_cast<const s8v*>(p);
}

// LLC-coherent 16B fragment load as 2x8B relaxed agent atomics (freshness;
// per-element atomicity not required — validity comes from the flag protocol)
__device__ inline s8v ld_b8_llc(const ushort* p){
  B8 b;
  const u64* q = (const u64*)p;
  b.ull[0] = __hip_atomic_load(q,   __ATOMIC_RELAXED, __HIP_MEMORY_SCOPE_AGENT);
  b.ull[1] = __hip_atomic_load(q+1, __ATOMIC_RELAXED, __HIP_MEMORY_SCOPE_AGENT);
  return b.v;
}

__device__ inline uint ald32(const uint* p){
  return __hip_atomic_load(p, __ATOMIC_RELAXED, __HIP_MEMORY_SCOPE_AGENT);
}
__device__ inline void ast32(uint* p, uint v){
  __hip_atomic_store(p, v, __ATOMIC_RELAXED, __HIP_MEMORY_SCOPE_AGENT);
}

__device__ inline s8v cvt8(float4 a, float4 b){
  B8 r;
  r.s[0]=f2bf(a.x); r.s[1]=f2bf(a.y); r.s[2]=f2bf(a.z); r.s[3]=f2bf(a.w);
  r.s[4]=f2bf(b.x); r.s[5]=f2bf(b.y); r.s[6]=f2bf(b.z); r.s[7]=f2bf(b.w);
  return r.v;
}

// issue 8 fragment loads (frags q*8 .. q*8+7); frag f at +f*32 ushorts
#define LOAD8(B, base, q) do { \
  B[0] = ld_b8_llc((base) + (q)*256 +   0); \
  B[1] = ld_b8_llc((base) + (q)*256 +  32); \
  B[2] = ld_b8_llc((base) + (q)*256 +  64); \
  B[3] = ld_b8_llc((base) + (q)*256 +  96); \
  B[4] = ld_b8_llc((base) + (q)*256 + 128); \
  B[5] = ld_b8_llc((base) + (q)*256 + 160); \
  B[6] = ld_b8_llc((base) + (q)*256 + 192); \
  B[7] = ld_b8_llc((base) + (q)*256 + 224); \
} while(0)

// ---------------- fp32 -> bf16 conversion (weights) ----------------
__global__ void cvt_kernel(const float* __restrict__ src, ushort* __restrict__ dst, int n){
  int i = (blockIdx.x * blockDim.x + threadIdx.x) * 4;
  if (i + 3 < n){
    float4 v = *reinterpret_cast<const float4*>(src + i);
    u64 p = (u64)f2bf(v.x)
          | ((u64)f2bf(v.y) << 16)
          | ((u64)f2bf(v.z) << 32)
          | ((u64)f2bf(v.w) << 48);
    *reinterpret_cast<u64*>(dst + i) = p;
  }
}

// ---------------- input projections: xz/xr/xn = X @ W^T + b (bf16 out) ----------------
__global__ void __launch_bounds__(256, 1)
proj3_kernel(const float* __restrict__ X,
             const ushort* __restrict__ W0, const ushort* __restrict__ W1, const ushort* __restrict__ W2,
             const float* __restrict__ bias0, const float* __restrict__ bias1, const float* __restrict__ bias2,
             ushort* __restrict__ C0, ushort* __restrict__ C1, ushort* __restrict__ C2)
{
  const int lane = threadIdx.x & 63;
  const int wave = threadIdx.x >> 6;
  const int l15  = lane & 15;
  const int krow = (lane >> 4) << 3;
  const int n0 = blockIdx.x * 64;
  const int m0 = blockIdx.y * 128 + wave * 32;

  const ushort* Ws[3] = {W0, W1, W2};
  const float*  Bs[3] = {bias0, bias1, bias2};
  ushort*       Cs[3] = {C0, C1, C2};

  f4v acc[2][3][4];
  #pragma unroll
  for (int ms = 0; ms < 2; ++ms)
    #pragma unroll
    for (int g = 0; g < 3; ++g)
      #pragma unroll
      for (int nn = 0; nn < 4; ++nn)
        acc[ms][g][nn] = (f4v){0.f,0.f,0.f,0.f};

  const float* a0 = X + (m0 + l15) * DIN + krow;
  const float* a1 = a0 + 16 * DIN;

  for (int k = 0; k < DIN; k += 32){
    s8v af[2];
    {
      const float4* p0 = reinterpret_cast<const float4*>(a0 + k);
      const float4* p1 = reinterpret_cast<const float4*>(a1 + k);
      af[0] = cvt8(p0[0], p0[1]);
      af[1] = cvt8(p1[0], p1[1]);
    }
    #pragma unroll
    for (int g = 0; g < 3; ++g){
      const ushort* W = Ws[g];
      #pragma unroll
      for (int nn = 0; nn < 4; ++nn){
        s8v bfr = ld_b8(W + (n0 + nn*16 + l15) * DIN + k + krow);
        acc[0][g][nn] = mfma16(af[0], bfr, acc[0][g][nn]);
        acc[1][g][nn] = mfma16(af[1], bfr, acc[1][g][nn]);
      }
    }
  }

  #pragma unroll
  for (int g = 0; g < 3; ++g){
    ushort* C = Cs[g];
    #pragma unroll
    for (int nn = 0; nn < 4; ++nn){
      const int n = n0 + nn*16 + l15;
      const float bv = Bs[g][n];
      #pragma unroll
      for (int ms = 0; ms < 2; ++ms){
        #pragma unroll
        for (int r = 0; r < 4; ++r){
          int m = m0 + ms*16 + ((lane>>4)<<2) + r;
          C[m * DH + n] = f2bf(acc[ms][g][nn][r] + bv);
        }
      }
    }
  }
}

// ---------------- output projection: C = hs @ Why^T + b (fp32 out) ----------------
__global__ void __launch_bounds__(256, 1)
gemm1_kernel(const ushort* __restrict__ A, const ushort* __restrict__ W,
             const float* __restrict__ bias, float* __restrict__ C)
{
  const int lane = threadIdx.x & 63;
  const int wave = threadIdx.x >> 6;
  const int l15  = lane & 15;
  const int krow = (lane >> 4) << 3;
  const int n0 = blockIdx.x * 128;
  const int m0 = blockIdx.y * 128 + wave * 32;

  f4v acc[2][8];
  #pragma unroll
  for (int ms = 0; ms < 2; ++ms)
    #pragma unroll
    for (int nn = 0; nn < 8; ++nn)
      acc[ms][nn] = (f4v){0.f,0.f,0.f,0.f};

  const ushort* a0 = A + (m0 + l15) * DH + krow;
  const ushort* a1 = a0 + 16 * DH;

  for (int k = 0; k < DH; k += 32){
    s8v af0 = ld_b8(a0 + k);
    s8v af1 = ld_b8(a1 + k);
    #pragma unroll
    for (int nn = 0; nn < 8; ++nn){
      s8v b = ld_b8(W + (n0 + nn*16 + l15) * DH + k + krow);
      acc[0][nn] = mfma16(af0, b, acc[0][nn]);
      acc[1][nn] = mfma16(af1, b, acc[1][nn]);
    }
  }

  #pragma unroll
  for (int nn = 0; nn < 8; ++nn){
    const int n = n0 + nn*16 + l15;
    const float bv = bias[n];
    #pragma unroll
    for (int ms = 0; ms < 2; ++ms){
      #pragma unroll
      for (int r = 0; r < 4; ++r){
        int m = m0 + ms*16 + ((lane>>4)<<2) + r;
        C[m * DH + n] = acc[ms][nn][r] + bv;
      }
    }
  }
}

// ---------------- the GRU scan ----------------
// 256 wgs x 64 thr (ONE wave each): wg = (group g = wid>>6 owning batches
// [16g,16g+16), tile jt = wid&63 owning 16 hidden cols) computes the FULL
// K=1024 itself: wz/wr register-stationary (64 frags = 256 VGPRs), wn in
// LDS (32 KB). No barriers, no cross-wave reduce, no sync-width union —
// the per-phase chain is poll -> pipelined 32-frag LLC load -> register
// MFMA -> lane-local activation (MFMA C-layout: z,r,n,h all at col=l15,
// rows hi2*4+r) -> packed store -> single-wave vmcnt drain -> flag.
// Protocol identical to R6 (proven): monotone flags, double-buffered
// h/rh slots, h0 = flag 1, rh(t) = flag t+1, h(t) = flag t+2.
__global__ void __launch_bounds__(64, 1)
scan_kernel(const ushort* __restrict__ xz, const ushort* __restrict__ xr,
            const ushort* __restrict__ xn,
            const ushort* __restrict__ Whz, const ushort* __restrict__ Whr,
            const ushort* __restrict__ Whn,
            const float* __restrict__ h0,
            ushort* __restrict__ hbuf,     // 2 x HSZ bf16
            ushort* __restrict__ rhbuf,    // 2 x HSZ bf16
            ushort* __restrict__ hs,       // 512*64*1024 bf16
            float*  __restrict__ hlast,    // 64*1024 f32
            uint* __restrict__ hflags,     // 256 wgs * 4 uints
            uint* __restrict__ rhflags)
{
  const int lane = threadIdx.x;       // 0..63
  const int l15  = lane & 15;
  const int hi2  = lane >> 4;         // 0..3
  const int wid  = blockIdx.x;
  const int g    = wid >> 6;          // batch group 0..3
  const int jt   = wid & 63;          // 16-col tile 0..63
  const int b0   = g << 4;
  const int j0   = jt << 4;

  __shared__ s8v wn_lds[32][64];      // 32 KB: frag f, lane l (conflict-free b128)

  // wz/wr register-stationary: 64 frags = 256 VGPRs. wn staged to LDS.
  s8v wz[32], wr[32];
  {
    const int wcol = (j0 + l15) * DH + hi2 * 8;
    #pragma unroll
    for (int f = 0; f < 32; ++f){
      wz[f] = ld_b8(Whz + wcol + f*32);
      wr[f] = ld_b8(Whr + wcol + f*32);
      wn_lds[f][lane] = ld_b8(Whn + wcol + f*32);
    }
  }

  // register h at this lane's output positions: rows b0+hi2*4+r, col j0+l15
  float hreg[4];
  #pragma unroll
  for (int r = 0; r < 4; ++r)
    hreg[r] = h0[(b0 + hi2*4 + r)*DH + j0 + l15];

  // init publish h_{-1} = h0 into slot 1 (t=0 reads slot (0^1)&1 = 1)
  #pragma unroll
  for (int r = 0; r < 4; ++r){
    ushort mybf = f2bf(hreg[r]);
    uint other = (uint)(ushort)__shfl_xor((int)mybf, 1, 64);
    if ((lane & 1) == 0){
      uint pack = (uint)mybf | (other << 16);
      ast32((uint*)(hbuf + HSZ + (b0 + hi2*4 + r)*DH + j0 + l15), pack);
    }
  }
  __asm__ volatile("s_waitcnt vmcnt(0)" ::: "memory");   // single-wave drain
  if (lane == 0) ast32(&hflags[wid*4], 1u);

  // lane l polls producer tile l of its group (full-K needs all 64)
  const uint* hfp  = hflags  + (g*64 + lane) * 4;
  const uint* rhfp = rhflags + (g*64 + lane) * 4;

  s8v A0[8], A1[8];                  // 2x8-frag ping-pong staging (64 VGPRs)

  #pragma unroll 1
  for (int t = 0; t < S_LEN; ++t){
    // prefetch this step's x values (independent of the polls)
    const size_t xb = (size_t)(t*BATCH + b0 + hi2*4) * DH + j0 + l15;
    float xzv[4], xrv[4], xnv[4];
    #pragma unroll
    for (int r = 0; r < 4; ++r){
      xzv[r] = bf2f(xz[xb + (size_t)r*DH]);
      xrv[r] = bf2f(xr[xb + (size_t)r*DH]);
      xnv[r] = bf2f(xn[xb + (size_t)r*DH]);
    }

    // ---- phase A: z, r ----
    {
      const uint tgt = (uint)(t + 1);
      while (true){
        uint v = ald32(hfp);
        if (__all(v >= tgt)) break;
        __builtin_amdgcn_s_sleep(1);
      }
    }
    __asm__ volatile("" ::: "memory");

    const ushort* ap = hbuf + ((t ^ 1) & 1) * HSZ + (b0 + l15) * DH + hi2*8;
    LOAD8(A0, ap, 0);
    LOAD8(A1, ap, 1);
    f4v az[2] = {(f4v){0.f,0.f,0.f,0.f}, (f4v){0.f,0.f,0.f,0.f}};
    f4v ar[2] = {(f4v){0.f,0.f,0.f,0.f}, (f4v){0.f,0.f,0.f,0.f}};
    #pragma unroll
    for (int i = 0; i < 8; ++i){
      az[i&1] = mfma16(A0[i], wz[i], az[i&1]);
      ar[i&1] = mfma16(A0[i], wr[i], ar[i&1]);
    }
    LOAD8(A0, ap, 2);
    #pragma unroll
    for (int i = 0; i < 8; ++i){
      az[i&1] = mfma16(A1[i], wz[8+i], az[i&1]);
      ar[i&1] = mfma16(A1[i], wr[8+i], ar[i&1]);
    }
    LOAD8(A1, ap, 3);
    #pragma unroll
    for (int i = 0; i < 8; ++i){
      az[i&1] = mfma16(A0[i], wz[16+i], az[i&1]);
      ar[i&1] = mfma16(A0[i], wr[16+i], ar[i&1]);
    }
    #pragma unroll
    for (int i = 0; i < 8; ++i){
      az[i&1] = mfma16(A1[i], wz[24+i], az[i&1]);
      ar[i&1] = mfma16(A1[i], wr[24+i], ar[i&1]);
    }

    float zz[4], rh[4];
    #pragma unroll
    for (int r = 0; r < 4; ++r){
      float sz = az[0][r] + az[1][r];
      float sr = ar[0][r] + ar[1][r];
      zz[r] = 1.f / (1.f + __expf(-(xzv[r] + sz)));
      float rv = 1.f / (1.f + __expf(-(xrv[r] + sr)));
      rh[r] = rv * hreg[r];
    }
    #pragma unroll
    for (int r = 0; r < 4; ++r){
      ushort mybf = f2bf(rh[r]);
      uint other = (uint)(ushort)__shfl_xor((int)mybf, 1, 64);
      if ((lane & 1) == 0){
        uint pack = (uint)mybf | (other << 16);
        ast32((uint*)(rhbuf + (t & 1)*HSZ + (b0 + hi2*4 + r)*DH + j0 + l15), pack);
      }
    }
    __asm__ volatile("s_waitcnt vmcnt(0)" ::: "memory");
    if (lane == 0) ast32(&rhflags[wid*4], (uint)(t + 1));

    // ---- phase B: n, h update ----
    {
      const uint tgt = (uint)(t + 1);
      while (true){
        uint v = ald32(rhfp);
        if (__all(v >= tgt)) break;
        __builtin_amdgcn_s_sleep(1);
      }
    }
    __asm__ volatile("" ::: "memory");

    const ushort* rp = rhbuf + (t & 1) * HSZ + (b0 + l15) * DH + hi2*8;
    LOAD8(A0, rp, 0);
    LOAD8(A1, rp, 1);
    f4v an[2] = {(f4v){0.f,0.f,0.f,0.f}, (f4v){0.f,0.f,0.f,0.f}};
    #pragma unroll
    for (int i = 0; i < 8; ++i)
      an[i&1] = mfma16(A0[i], wn_lds[i][lane], an[i&1]);
    LOAD8(A0, rp, 2);
    #pragma unroll
    for (int i = 0; i < 8; ++i)
      an[i&1] = mfma16(A1[i], wn_lds[8+i][lane], an[i&1]);
    LOAD8(A1, rp, 3);
    #pragma unroll
    for (int i = 0; i < 8; ++i)
      an[i&1] = mfma16(A0[i], wn_lds[16+i][lane], an[i&1]);
    #pragma unroll
    for (int i = 0; i < 8; ++i)
      an[i&1] = mfma16(A1[i], wn_lds[24+i][lane], an[i&1]);

    #pragma unroll
    for (int r = 0; r < 4; ++r){
      float pre = xnv[r] + an[0][r] + an[1][r];
      float e = __expf(2.f * pre);
      float nv = 1.f - 2.f / (e + 1.f);
      hreg[r] = hreg[r] + zz[r] * (nv - hreg[r]);
    }

    #pragma unroll
    for (int r = 0; r < 4; ++r){
      ushort mybf = f2bf(hreg[r]);
      uint other = (uint)(ushort)__shfl_xor((int)mybf, 1, 64);
      const int row = b0 + hi2*4 + r;
      if ((lane & 1) == 0){
        uint pack = (uint)mybf | (other << 16);
        ast32((uint*)(hbuf + (t & 1)*HSZ + row*DH + j0 + l15), pack);
        *reinterpret_cast<uint*>(hs + (size_t)(t*BATCH + row)*DH + j0 + l15) = pack;
      }
    }
    if (t == S_LEN - 1){
      #pragma unroll
      for (int r = 0; r < 4; ++r)
        hlast[(b0 + hi2*4 + r)*DH + j0 + l15] = hreg[r];
    }
    __asm__ volatile("s_waitcnt vmcnt(0)" ::: "memory");
    if (lane == 0) ast32(&hflags[wid*4], (uint)(t + 2));
  }
}

extern "C" void kernel_launch(void* const* d_in, const int* in_sizes, int n_in,
                              void* d_out, int out_size, void* d_ws, size_t ws_size,
                              hipStream_t stream) {
  const float* x_seq = (const float*)d_in[0];
  const float* h0    = (const float*)d_in[1];
  const float* Wxz_w = (const float*)d_in[2];
  const float* Wxz_b = (const float*)d_in[3];
  const float* Whz_w = (const float*)d_in[4];
  const float* Wxr_w = (const float*)d_in[5];
  const float* Wxr_b = (const float*)d_in[6];
  const float* Whr_w = (const float*)d_in[7];
  const float* Wxn_w = (const float*)d_in[8];
  const float* Wxn_b = (const float*)d_in[9];
  const float* Whn_w = (const float*)d_in[10];
  const float* Why_w = (const float*)d_in[11];
  const float* Why_b = (const float*)d_in[12];

  const size_t MiB = 1u << 20;
  unsigned char* ws = (unsigned char*)d_ws;

  ushort* Whz16 = (ushort*)(ws + 0*MiB);
  ushort* Whr16 = (ushort*)(ws + 2*MiB);
  ushort* Whn16 = (ushort*)(ws + 4*MiB);
  ushort* Wxz16 = (ushort*)(ws + 6*MiB);
  ushort* Wxr16 = (ushort*)(ws + 8*MiB);
  ushort* Wxn16 = (ushort*)(ws + 10*MiB);
  ushort* Why16 = (ushort*)(ws + 12*MiB);
  ushort* xn_buf = (ushort*)(ws + 16*MiB);          // 64 MiB
  ushort* hs     = (ushort*)(ws + 80*MiB);          // 64 MiB
  ushort* hbuf   = (ushort*)(ws + 144*MiB);         // 256 KiB (2 slots)
  ushort* rhbuf  = (ushort*)(ws + 144*MiB + 256*1024);
  uint*   hflags = (uint*)  (ws + 144*MiB + 512*1024);        // 4 KiB
  uint*   rhflags= (uint*)  (ws + 144*MiB + 512*1024 + 4096); // 4 KiB

  // xz/xr live in d_out as bf16 scratch (overwritten by gemm1 later; h_last tail disjoint)
  ushort* xz_buf = (ushort*)d_out;                  // 64 MiB
  ushort* xr_buf = xz_buf + (size_t)S_LEN*BATCH*DH; // 64 MiB
  float*  out_f  = (float*)d_out;
  float*  hlast  = out_f + (size_t)S_LEN*BATCH*DH;

  const int NW = DH * DIN; // 1048576 elems per weight matrix

  cvt_kernel<<<1024, 256, 0, stream>>>(Whz_w, Whz16, NW);
  cvt_kernel<<<1024, 256, 0, stream>>>(Whr_w, Whr16, NW);
  cvt_kernel<<<1024, 256, 0, stream>>>(Whn_w, Whn16, NW);
  cvt_kernel<<<1024, 256, 0, stream>>>(Wxz_w, Wxz16, NW);
  cvt_kernel<<<1024, 256, 0, stream>>>(Wxr_w, Wxr16, NW);
  cvt_kernel<<<1024, 256, 0, stream>>>(Wxn_w, Wxn16, NW);
  cvt_kernel<<<1024, 256, 0, stream>>>(Why_w, Why16, NW);

  proj3_kernel<<<dim3(16, 256), 256, 0, stream>>>(
      x_seq, Wxz16, Wxr16, Wxn16, Wxz_b, Wxr_b, Wxn_b, xz_buf, xr_buf, xn_buf);

  // flags: monotone, re-poisoned to 0 each launch (hflags + rhflags = 8 KiB)
  hipMemsetAsync((void*)hflags, 0, 8192, stream);

  scan_kernel<<<256, 64, 0, stream>>>(
      xz_buf, xr_buf, xn_buf, Whz16, Whr16, Whn16, h0,
      hbuf, rhbuf, hs, hlast, hflags, rhflags);

  gemm1_kernel<<<dim3(8, 256), 256, 0, stream>>>(hs, Why16, Why_b, out_f);
}

// Round 9
// 7341.454 us; speedup vs baseline: 1.3418x; 1.3418x over previous
//
#include <hip/hip_runtime.h>

typedef unsigned int uint;
typedef unsigned short ushort;
typedef unsigned long long u64;

// MFMA fragment types (16x16x32 bf16 -> 8 bf16 in, 4 fp32 acc)
typedef short s8v __attribute__((ext_vector_type(8)));
typedef float f4v __attribute__((ext_vector_type(4)));

#define S_LEN 512
#define BATCH 64
#define DH    1024
#define DIN   1024

union B8 { s8v v; uint u[4]; u64 ull[2]; ushort s[8]; };

__device__ inline ushort f2bf(float f){
  uint u = __builtin_bit_cast(uint, f);
  u += 0x7fffu + ((u >> 16) & 1u);
  return (ushort)(u >> 16);
}
__device__ inline float bf2f(ushort s){
  uint u = ((uint)s) << 16;
  return __builtin_bit_cast(float, u);
}

__device__ inline f4v mfma16(s8v a, s8v b, f4v c){
  return __builtin_amdgcn_mfma_f32_16x16x32_bf16(a, b, c, 0, 0, 0);
}

__device__ inline s8v ld_b8(const ushort* p){
  return *reinterpret_cast<const s8v*>(p);
}

__device__ inline u64 ald64(const u64* p){
  return __hip_atomic_load(p, __ATOMIC_RELAXED, __HIP_MEMORY_SCOPE_AGENT);
}
__device__ inline uint ald32(const uint* p){
  return __hip_atomic_load(p, __ATOMIC_RELAXED, __HIP_MEMORY_SCOPE_AGENT);
}
__device__ inline void ast32(uint* p, uint v){
  __hip_atomic_store(p, v, __ATOMIC_RELAXED, __HIP_MEMORY_SCOPE_AGENT);
}

__device__ inline s8v cvt8(float4 a, float4 b){
  B8 r;
  r.s[0]=f2bf(a.x); r.s[1]=f2bf(a.y); r.s[2]=f2bf(a.z); r.s[3]=f2bf(a.w);
  r.s[4]=f2bf(b.x); r.s[5]=f2bf(b.y); r.s[6]=f2bf(b.z); r.s[7]=f2bf(b.w);
  return r.v;
}

// ---- tagged-data exchange ----
// Every 4B word of the exchange buffers carries 1 tag bit in the bf16
// mantissa LSB of its even column; a u64 (4 cols) thus carries a 2-bit
// mod-4 step tag at bits 0 and 32. The poll load IS the data load (1 LLC
// RTT per phase, no producer drain, no flag). Mod-4 exact match is
// alias-safe: protocol gating bounds inter-wg skew to <2 steps, and same
// tag recurs only at distance 4. Termination is absolute: per-poll guard
// (8192 rounds ~0.5ms >> any legitimate wait) + global abort latch (first
// exhaustion flips it; all other polls bail within 64 rounds).
#define TAGMASK 0x0000000100000001ull
__device__ inline u64 tagpat(uint tag){
  return (u64)(tag & 1u) | ((u64)((tag >> 1) & 1u) << 32);
}

// poll the wave's 8 A-fragments (16 u64) until all tags match
__device__ inline void poll16(const u64* __restrict__ p, uint tag, B8 (&fr)[8],
                              uint* __restrict__ abortv){
  const u64 pat = tagpat(tag);
  #pragma unroll
  for (int i = 0; i < 8; ++i){
    fr[i].ull[0] = ald64(p + i*8);
    fr[i].ull[1] = ald64(p + i*8 + 1);
  }
  uint pend = 0xFFFFu;
  int guard = 0;
  while (true){
    uint np = 0;
    #pragma unroll
    for (int i = 0; i < 8; ++i){
      if ((pend >> (2*i)) & 1u)
        if (((fr[i].ull[0] ^ pat) & TAGMASK) != 0) np |= 1u << (2*i);
      if ((pend >> (2*i+1)) & 1u)
        if (((fr[i].ull[1] ^ pat) & TAGMASK) != 0) np |= 1u << (2*i+1);
    }
    pend = np;
    if (__all(pend == 0)) break;
    ++guard;
    if (guard > 8192){ ast32(abortv, 1u); break; }          // latch + bail
    if ((guard & 63) == 0 && ald32(abortv) != 0) break;     // others bail fast
    __builtin_amdgcn_s_sleep(1);
    #pragma unroll
    for (int i = 0; i < 8; ++i){
      if ((pend >> (2*i)) & 1u)   fr[i].ull[0] = ald64(p + i*8);
      if ((pend >> (2*i+1)) & 1u) fr[i].ull[1] = ald64(p + i*8 + 1);
    }
  }
}

// ---------------- fp32 -> bf16 conversion (weights) ----------------
__global__ void cvt_kernel(const float* __restrict__ src, ushort* __restrict__ dst, int n){
  int i = (blockIdx.x * blockDim.x + threadIdx.x) * 4;
  if (i + 3 < n){
    float4 v = *reinterpret_cast<const float4*>(src + i);
    u64 p = (u64)f2bf(v.x)
          | ((u64)f2bf(v.y) << 16)
          | ((u64)f2bf(v.z) << 32)
          | ((u64)f2bf(v.w) << 48);
    *reinterpret_cast<u64*>(dst + i) = p;
  }
}

// ---------------- input projections: xz/xr/xn = X @ W^T + b (bf16 out) ----------------
__global__ void __launch_bounds__(256, 1)
proj3_kernel(const float* __restrict__ X,
             const ushort* __restrict__ W0, const ushort* __restrict__ W1, const ushort* __restrict__ W2,
             const float* __restrict__ bias0, const float* __restrict__ bias1, const float* __restrict__ bias2,
             ushort* __restrict__ C0, ushort* __restrict__ C1, ushort* __restrict__ C2)
{
  const int lane = threadIdx.x & 63;
  const int wave = threadIdx.x >> 6;
  const int l15  = lane & 15;
  const int krow = (lane >> 4) << 3;
  const int n0 = blockIdx.x * 64;
  const int m0 = blockIdx.y * 128 + wave * 32;

  const ushort* Ws[3] = {W0, W1, W2};
  const float*  Bs[3] = {bias0, bias1, bias2};
  ushort*       Cs[3] = {C0, C1, C2};

  f4v acc[2][3][4];
  #pragma unroll
  for (int ms = 0; ms < 2; ++ms)
    #pragma unroll
    for (int g = 0; g < 3; ++g)
      #pragma unroll
      for (int nn = 0; nn < 4; ++nn)
        acc[ms][g][nn] = (f4v){0.f,0.f,0.f,0.f};

  const float* a0 = X + (m0 + l15) * DIN + krow;
  const float* a1 = a0 + 16 * DIN;

  for (int k = 0; k < DIN; k += 32){
    s8v af[2];
    {
      const float4* p0 = reinterpret_cast<const float4*>(a0 + k);
      const float4* p1 = reinterpret_cast<const float4*>(a1 + k);
      af[0] = cvt8(p0[0], p0[1]);
      af[1] = cvt8(p1[0], p1[1]);
    }
    #pragma unroll
    for (int g = 0; g < 3; ++g){
      const ushort* W = Ws[g];
      #pragma unroll
      for (int nn = 0; nn < 4; ++nn){
        s8v bfr = ld_b8(W + (n0 + nn*16 + l15) * DIN + k + krow);
        acc[0][g][nn] = mfma16(af[0], bfr, acc[0][g][nn]);
        acc[1][g][nn] = mfma16(af[1], bfr, acc[1][g][nn]);
      }
    }
  }

  #pragma unroll
  for (int g = 0; g < 3; ++g){
    ushort* C = Cs[g];
    #pragma unroll
    for (int nn = 0; nn < 4; ++nn){
      const int n = n0 + nn*16 + l15;
      const float bv = Bs[g][n];
      #pragma unroll
      for (int ms = 0; ms < 2; ++ms){
        #pragma unroll
        for (int r = 0; r < 4; ++r){
          int m = m0 + ms*16 + ((lane>>4)<<2) + r;
          C[m * DH + n] = f2bf(acc[ms][g][nn][r] + bv);
        }
      }
    }
  }
}

// ---------------- output projection: C = hs @ Why^T + b (fp32 out) ----------------
__global__ void __launch_bounds__(256, 1)
gemm1_kernel(const ushort* __restrict__ A, const ushort* __restrict__ W,
             const float* __restrict__ bias, float* __restrict__ C)
{
  const int lane = threadIdx.x & 63;
  const int wave = threadIdx.x >> 6;
  const int l15  = lane & 15;
  const int krow = (lane >> 4) << 3;
  const int n0 = blockIdx.x * 128;
  const int m0 = blockIdx.y * 128 + wave * 32;

  f4v acc[2][8];
  #pragma unroll
  for (int ms = 0; ms < 2; ++ms)
    #pragma unroll
    for (int nn = 0; nn < 8; ++nn)
      acc[ms][nn] = (f4v){0.f,0.f,0.f,0.f};

  const ushort* a0 = A + (m0 + l15) * DH + krow;
  const ushort* a1 = a0 + 16 * DH;

  for (int k = 0; k < DH; k += 32){
    s8v af0 = ld_b8(a0 + k);
    s8v af1 = ld_b8(a1 + k);
    #pragma unroll
    for (int nn = 0; nn < 8; ++nn){
      s8v b = ld_b8(W + (n0 + nn*16 + l15) * DH + k + krow);
      acc[0][nn] = mfma16(af0, b, acc[0][nn]);
      acc[1][nn] = mfma16(af1, b, acc[1][nn]);
    }
  }

  #pragma unroll
  for (int nn = 0; nn < 8; ++nn){
    const int n = n0 + nn*16 + l15;
    const float bv = bias[n];
    #pragma unroll
    for (int ms = 0; ms < 2; ++ms){
      #pragma unroll
      for (int r = 0; r < 4; ++r){
        int m = m0 + ms*16 + ((lane>>4)<<2) + r;
        C[m * DH + n] = acc[ms][nn][r] + bv;
      }
    }
  }
}

// ---------------- the GRU scan ----------------
// EXACTLY the R6 shape (measured 4244us): 128 wgs x 256 thr, wg = (group
// g = wid>>5 owning batches [16g,16g+16), j-tile jt = wid&31 owning 32
// cols), 4 waves K-split (256 each), wz/wr/wn register-declared, redA/redB
// 24KB LDS, per-thread 4B packed stores. ONLY the exchange protocol is
// swapped: flags+drain -> in-mantissa mod-4 tags (see poll16). Tags:
// h written at step t -> (t+2)&3 (h0 init -> 1); rh at step t -> (t+1)&3;
// phase A of step t expects (t+1)&3 on h, phase B expects (t+1)&3 on rh.
// Single-slot reuse safe: a wg's write for step T+1 is gated through its
// intra-wg barrier on all 4 waves' polls of step T, which union over all
// 32 producers; so every consumer's read of T precedes any overwrite.
__global__ void __launch_bounds__(256, 1)
scan_kernel(const ushort* __restrict__ xz, const ushort* __restrict__ xr,
            const ushort* __restrict__ xn,
            const ushort* __restrict__ Whz, const ushort* __restrict__ Whr,
            const ushort* __restrict__ Whn,
            const float* __restrict__ h0,
            ushort* __restrict__ hbuf,     // 64*1024 bf16, tagged single slot
            ushort* __restrict__ rhbuf,    // 64*1024 bf16, tagged single slot
            ushort* __restrict__ hs,       // 512*64*1024 bf16 (clean)
            float*  __restrict__ hlast,    // 64*1024 f32
            uint*   __restrict__ abortv)   // global abort latch
{
  const int tid  = threadIdx.x;
  const int wave = tid >> 6;          // 0..3 = K-quarter
  const int lane = tid & 63;
  const int l15  = lane & 15;
  const int hi2  = lane >> 4;         // 0..3
  const int krow = hi2 << 3;          // 0,8,16,24
  const int wid  = blockIdx.x;
  const int g    = wid >> 5;          // batch group 0..3
  const int jt   = wid & 31;          // j-tile 0..31
  const int b0   = g << 4;
  const int j0   = jt << 5;           // 32 cols per wg
  const int kbase = wave << 8;        // 0,256,512,768

  __shared__ float redA[2][4][512];   // [z/r][wave][16 rows x 32 cols]
  __shared__ float redB[4][512];      // n partials

  // register-stationary recurrent weights (R6 layout)
  s8v wz[2][8], wr[2][8], wn[2][8];
  #pragma unroll
  for (int nn = 0; nn < 2; ++nn){
    const int wbase = (j0 + nn*16 + l15) * DH + kbase + krow;
    #pragma unroll
    for (int kk = 0; kk < 8; ++kk){
      wz[nn][kk] = ld_b8(Whz + wbase + kk*32);
      wr[nn][kk] = ld_b8(Whr + wbase + kk*32);
      wn[nn][kk] = ld_b8(Whn + wbase + kk*32);
    }
  }

  // per-thread owned output pair: row brow, cols jcol, jcol+1
  const int bl   = tid >> 4;          // 0..15
  const int jl2  = (tid & 15) << 1;   // 0,2,...,30
  const int brow = b0 + bl;
  const int jcol = j0 + jl2;
  const uint myb = (uint)((jl2 >> 1) & 1);  // 0: low half of u64 (tag bit0), 1: high (bit1)
  float2 h2 = *reinterpret_cast<const float2*>(h0 + brow * DH + jcol);
  float hr0 = h2.x, hr1 = h2.y;

  // init publish h_{-1} = h0 with tag 1 (bit0=1, bit1=0)
  {
    uint tbit = myb ? 0u : 1u;
    uint pack = ((uint)(f2bf(hr0) & 0xFFFEu) | tbit) | ((uint)f2bf(hr1) << 16);
    ast32((uint*)(hbuf + brow*DH + jcol), pack);
  }

  const u64* hpo  = (const u64*)(hbuf  + (b0 + l15)*DH + kbase + krow);
  const u64* rhpo = (const u64*)(rhbuf + (b0 + l15)*DH + kbase + krow);
  const int e0 = bl*32 + jl2;

  B8 fr[8];
  float z0 = 0.f, z1 = 0.f;

  #pragma unroll 1
  for (int t = 0; t < S_LEN; ++t){
    const int xidx = (t * BATCH + brow) * DH + jcol;

    // prefetch this step's x values (independent of the polls)
    uint xzp = *reinterpret_cast<const uint*>(xz + xidx);
    uint xrp = *reinterpret_cast<const uint*>(xr + xidx);
    uint xnp = *reinterpret_cast<const uint*>(xn + xidx);

    // ---- phase A: z, r ----
    poll16(hpo, (uint)(t + 1) & 3u, fr, abortv);

    f4v az[2] = {(f4v){0.f,0.f,0.f,0.f}, (f4v){0.f,0.f,0.f,0.f}};
    f4v ar[2] = {(f4v){0.f,0.f,0.f,0.f}, (f4v){0.f,0.f,0.f,0.f}};
    #pragma unroll
    for (int kk = 0; kk < 8; ++kk){
      s8v a = fr[kk].v;
      az[0] = mfma16(a, wz[0][kk], az[0]);
      az[1] = mfma16(a, wz[1][kk], az[1]);
      ar[0] = mfma16(a, wr[0][kk], ar[0]);
      ar[1] = mfma16(a, wr[1][kk], ar[1]);
    }
    #pragma unroll
    for (int nn = 0; nn < 2; ++nn)
      #pragma unroll
      for (int r = 0; r < 4; ++r){
        const int e = (hi2*4 + r)*32 + nn*16 + l15;
        redA[0][wave][e] = az[nn][r];
        redA[1][wave][e] = ar[nn][r];
      }
    __syncthreads();

    float sz0 = redA[0][0][e0]   + redA[0][1][e0]   + redA[0][2][e0]   + redA[0][3][e0];
    float sz1 = redA[0][0][e0+1] + redA[0][1][e0+1] + redA[0][2][e0+1] + redA[0][3][e0+1];
    float sr0 = redA[1][0][e0]   + redA[1][1][e0]   + redA[1][2][e0]   + redA[1][3][e0];
    float sr1 = redA[1][0][e0+1] + redA[1][1][e0+1] + redA[1][2][e0+1] + redA[1][3][e0+1];
    z0 = 1.f / (1.f + __expf(-(bf2f((ushort)(xzp & 0xFFFFu)) + sz0)));
    z1 = 1.f / (1.f + __expf(-(bf2f((ushort)(xzp >> 16))     + sz1)));
    float r0 = 1.f / (1.f + __expf(-(bf2f((ushort)(xrp & 0xFFFFu)) + sr0)));
    float r1 = 1.f / (1.f + __expf(-(bf2f((ushort)(xrp >> 16))     + sr1)));
    float rh0 = r0 * hr0;
    float rh1 = r1 * hr1;
    {
      const uint tg = (uint)(t + 1) & 3u;
      uint tbit = myb ? ((tg >> 1) & 1u) : (tg & 1u);
      uint pack = ((uint)(f2bf(rh0) & 0xFFFEu) | tbit) | ((uint)f2bf(rh1) << 16);
      ast32((uint*)(rhbuf + brow*DH + jcol), pack);   // no drain, no flag
    }

    // ---- phase B: n, h update ----
    poll16(rhpo, (uint)(t + 1) & 3u, fr, abortv);

    f4v an[2] = {(f4v){0.f,0.f,0.f,0.f}, (f4v){0.f,0.f,0.f,0.f}};
    #pragma unroll
    for (int kk = 0; kk < 8; ++kk){
      s8v a = fr[kk].v;
      an[0] = mfma16(a, wn[0][kk], an[0]);
      an[1] = mfma16(a, wn[1][kk], an[1]);
    }
    #pragma unroll
    for (int nn = 0; nn < 2; ++nn)
      #pragma unroll
      for (int r = 0; r < 4; ++r)
        redB[wave][(hi2*4 + r)*32 + nn*16 + l15] = an[nn][r];
    __syncthreads();

    float sn0 = redB[0][e0]   + redB[1][e0]   + redB[2][e0]   + redB[3][e0];
    float sn1 = redB[0][e0+1] + redB[1][e0+1] + redB[2][e0+1] + redB[3][e0+1];
    float pre0 = bf2f((ushort)(xnp & 0xFFFFu)) + sn0;
    float pre1 = bf2f((ushort)(xnp >> 16))     + sn1;
    float e_0 = __expf(2.f * pre0);
    float e_1 = __expf(2.f * pre1);
    float n0 = 1.f - 2.f / (e_0 + 1.f);
    float n1 = 1.f - 2.f / (e_1 + 1.f);
    float hn0 = hr0 + z0 * (n0 - hr0);
    float hn1 = hr1 + z1 * (n1 - hr1);
    hr0 = hn0; hr1 = hn1;

    // clean values to hs; tagged values to the exchange slot
    uint cpack = (uint)f2bf(hn0) | ((uint)f2bf(hn1) << 16);
    *reinterpret_cast<uint*>(hs + xidx) = cpack;
    {
      const uint tg = (uint)(t + 2) & 3u;
      uint tbit = myb ? ((tg >> 1) & 1u) : (tg & 1u);
      uint tpack = (cpack & ~1u) | tbit;
      ast32((uint*)(hbuf + brow*DH + jcol), tpack);
    }
    if (t == S_LEN - 1){
      float2 hl; hl.x = hn0; hl.y = hn1;
      *reinterpret_cast<float2*>(hlast + brow*DH + jcol) = hl;
    }
  }
}

extern "C" void kernel_launch(void* const* d_in, const int* in_sizes, int n_in,
                              void* d_out, int out_size, void* d_ws, size_t ws_size,
                              hipStream_t stream) {
  const float* x_seq = (const float*)d_in[0];
  const float* h0    = (const float*)d_in[1];
  const float* Wxz_w = (const float*)d_in[2];
  const float* Wxz_b = (const float*)d_in[3];
  const float* Whz_w = (const float*)d_in[4];
  const float* Wxr_w = (const float*)d_in[5];
  const float* Wxr_b = (const float*)d_in[6];
  const float* Whr_w = (const float*)d_in[7];
  const float* Wxn_w = (const float*)d_in[8];
  const float* Wxn_b = (const float*)d_in[9];
  const float* Whn_w = (const float*)d_in[10];
  const float* Why_w = (const float*)d_in[11];
  const float* Why_b = (const float*)d_in[12];

  const size_t MiB = 1u << 20;
  unsigned char* ws = (unsigned char*)d_ws;

  ushort* Whz16 = (ushort*)(ws + 0*MiB);
  ushort* Whr16 = (ushort*)(ws + 2*MiB);
  ushort* Whn16 = (ushort*)(ws + 4*MiB);
  ushort* Wxz16 = (ushort*)(ws + 6*MiB);
  ushort* Wxr16 = (ushort*)(ws + 8*MiB);
  ushort* Wxn16 = (ushort*)(ws + 10*MiB);
  ushort* Why16 = (ushort*)(ws + 12*MiB);
  ushort* xn_buf = (ushort*)(ws + 16*MiB);          // 64 MiB
  ushort* hs     = (ushort*)(ws + 80*MiB);          // 64 MiB (clean, for gemm1)
  ushort* hbuf   = (ushort*)(ws + 144*MiB);         // 128 KiB single slot (tagged)
  ushort* rhbuf  = (ushort*)(ws + 144*MiB + 128*1024); // 128 KiB single slot (tagged)
  uint*   abortv = (uint*)  (ws + 144*MiB + 256*1024); // abort latch

  // xz/xr live in d_out as bf16 scratch (overwritten by gemm1 later; h_last tail disjoint)
  ushort* xz_buf = (ushort*)d_out;                  // 64 MiB
  ushort* xr_buf = xz_buf + (size_t)S_LEN*BATCH*DH; // 64 MiB
  float*  out_f  = (float*)d_out;
  float*  hlast  = out_f + (size_t)S_LEN*BATCH*DH;

  const int NW = DH * DIN; // 1048576 elems per weight matrix

  cvt_kernel<<<1024, 256, 0, stream>>>(Whz_w, Whz16, NW);
  cvt_kernel<<<1024, 256, 0, stream>>>(Whr_w, Whr16, NW);
  cvt_kernel<<<1024, 256, 0, stream>>>(Whn_w, Whn16, NW);
  cvt_kernel<<<1024, 256, 0, stream>>>(Wxz_w, Wxz16, NW);
  cvt_kernel<<<1024, 256, 0, stream>>>(Wxr_w, Wxr16, NW);
  cvt_kernel<<<1024, 256, 0, stream>>>(Wxn_w, Wxn16, NW);
  cvt_kernel<<<1024, 256, 0, stream>>>(Why_w, Why16, NW);

  proj3_kernel<<<dim3(16, 256), 256, 0, stream>>>(
      x_seq, Wxz16, Wxr16, Wxn16, Wxz_b, Wxr_b, Wxn_b, xz_buf, xr_buf, xn_buf);

  // poison both exchange slots to tag 0 (expected tags at t=0 are 1) and
  // clear the abort latch
  hipMemsetAsync((void*)hbuf, 0, 256*1024 + 4096, stream);

  scan_kernel<<<128, 256, 0, stream>>>(
      xz_buf, xr_buf, xn_buf, Whz16, Whr16, Whn16, h0,
      hbuf, rhbuf, hs, hlast, abortv);

  gemm1_kernel<<<dim3(8, 256), 256, 0, stream>>>(hs, Why16, Why_b, out_f);
}